// Round 12
// baseline (145.239 us; speedup 1.0000x reference)
//
#include <hip/hip_runtime.h>

#define N_NODES 100000
#define N_EDGES 1600000
#define IN_CH 8
#define HID_CH 64
#define OUT_CH 2

// 1024 dst-ranges of 98 nodes (1024*98 = 100352 >= 100000).
#define R2   1024
#define RN   98
#define CAP  1920    // per-range capacity; Binom mean 1568, sd ~40 -> +8.9σ
#define CSTRIDE 16   // cursor padded to one range per 64B line

// Round-12 binning: SINGLE CHANGE vs round 11 -> NB 128->256 so the grid
// covers all 256 CUs (R11 ran 128 blocks = half the GPU idle; every binning
// variant lands 17±3us, and CU coverage is the one lever not yet tested).
// Block b owns a distinct 6250-edge chunk: LDS histogram -> 1024-wide scan ->
// padded global cursor reservation -> L2/L3-hot re-read placing edges
// range-sorted into a 25KB LDS stage -> per-wave coalesced span dump.
#define NB   256
#define CH   (N_EDGES / NB)   // 6250 edges per chunk
#define CH2  (CH / 2)         // 3125 int2

// ---- workspace (4-byte words), ~9 MB ----
//   cursor : R2*CSTRIDE @ 0          (memset 0; per-range fill count, padded)
//   bucket : R2*CAP     @ WS_BUCKET  (packed (dl<<17)|src; csr overwrites in place)
//   offdeg : R2*RN      @ WS_OFFDEG  (per node: off | deg<<16, range-local)
//   g      : N*2 float  @ WS_G       (W_l2 @ h per node)
#define WS_BUCKET (R2 * CSTRIDE)
#define WS_OFFDEG (WS_BUCKET + R2 * CAP)
#define WS_G      (WS_OFFDEG + R2 * RN)

__global__ __launch_bounds__(1024) void bucket_sort(
        const int* __restrict__ src, const int* __restrict__ dst,
        int* __restrict__ cursor, int* __restrict__ bucket) {
    __shared__ int stage[CH];    // 25KB: chunk's edges, range-sorted (exact fit)
    __shared__ int cnt[R2];      // per-range count within this chunk
    __shared__ int loc[R2];      // local exclusive offsets (dump base)
    __shared__ int lcur[R2];     // placement cursors
    __shared__ int base[R2];     // reserved global span base
    __shared__ int wsum[16];
    int tid = threadIdx.x;       // 1024 threads == R2: no loops over ranges
    int w = tid >> 6;
    int lane = tid & 63;

    cnt[tid] = 0;
    __syncthreads();

    const int2* dch = (const int2*)(dst + (size_t)blockIdx.x * CH);
    const int2* sch = (const int2*)(src + (size_t)blockIdx.x * CH);

    // Pass 1: histogram over ranges.
    for (int i = tid; i < CH2; i += 1024) {
        int2 d = dch[i];
        atomicAdd(&cnt[(unsigned)d.x / RN], 1);
        atomicAdd(&cnt[(unsigned)d.y / RN], 1);
    }
    __syncthreads();

    // 1024-entry exclusive scan: per-wave shfl scan + wave-total scan.
    int v = cnt[tid];
    int incl = v;
    #pragma unroll
    for (int dd = 1; dd < 64; dd <<= 1) {
        int t2 = __shfl_up(incl, dd);
        if (lane >= dd) incl += t2;
    }
    if (lane == 63) wsum[w] = incl;
    loc[tid] = incl - v;
    __syncthreads();
    if (w == 0 && lane < 16) {
        int s = wsum[lane];
        int si = s;
        #pragma unroll
        for (int dd = 1; dd < 16; dd <<= 1) {
            int t2 = __shfl_up(si, dd);
            if (lane >= dd) si += t2;
        }
        wsum[lane] = si - s;
    }
    __syncthreads();
    {
        int o = loc[tid] + wsum[w];
        loc[tid] = o;
        lcur[tid] = o;
        // Reserve global span (padded line per range; 256 contenders/addr).
        base[tid] = (v > 0) ? atomicAdd(&cursor[tid * CSTRIDE], v) : 0;
    }
    __syncthreads();

    // Pass 2 (L2/L3-hot re-read): place edges range-sorted into LDS stage.
    // stage is an exact permutation of the chunk -> no overflow possible.
    for (int i = tid; i < CH2; i += 1024) {
        int2 d = dch[i];
        int2 s = sch[i];
        {
            unsigned r = (unsigned)d.x / RN;
            unsigned dl = (unsigned)d.x - r * RN;
            int p = atomicAdd(&lcur[r], 1);
            stage[p] = (int)((dl << 17) | (unsigned)s.x);
        }
        {
            unsigned r = (unsigned)d.y / RN;
            unsigned dl = (unsigned)d.y - r * RN;
            int p = atomicAdd(&lcur[r], 1);
            stage[p] = (int)((dl << 17) | (unsigned)s.y);
        }
    }
    __syncthreads();

    // Dump: wave w handles ranges [64w, 64w+64); each range's ~6-int span is
    // lane-contiguous in global (coalesced; ~2.6 writer-blocks per 64B line —
    // accepted to isolate the CU-coverage variable).
    for (int r = (w << 6); r < (w << 6) + 64; ++r) {
        int c = cnt[r];
        int b = base[r];
        int lo = loc[r];
        for (int j = lane; j < c; j += 64) {
            int slot = b + j;
            if (slot < CAP)
                bucket[(size_t)r * CAP + slot] = stage[lo + j];
        }
    }
}

// Layer 1 (exact round-8 version): LDS counting-sort of the range's edges to
// node order, 4-lane-per-node walk + distributed MLP. Dumps sorted CSR in
// place over the bucket region + offdeg for the layer-2 gather walk.
__global__ __launch_bounds__(512) void sage1_range(
        const int* __restrict__ bucket, const int* __restrict__ cursor,
        const float* __restrict__ x,
        const float* __restrict__ W_l1, const float* __restrict__ b_l1,
        const float* __restrict__ W_r1,
        const float* __restrict__ W_l2, const float* __restrict__ b_l2,
        const float* __restrict__ W_r2,
        int* __restrict__ csr, int* __restrict__ offdeg,
        float* __restrict__ g, float* __restrict__ out_rt) {
    __shared__ int raw[CAP];
    __shared__ int seg[CAP];
    __shared__ int scnt[128];
    __shared__ int soff[128];
    __shared__ int scur[128];
    __shared__ int wtot[2];
    __shared__ float sWl[HID_CH * IN_CH];
    __shared__ float sWr[HID_CH * IN_CH];
    __shared__ float sb[HID_CH];
    __shared__ float sWl2[OUT_CH * HID_CH];
    __shared__ float sWr2[OUT_CH * HID_CH];
    __shared__ float sb2[OUT_CH];

    int tid = threadIdx.x;
    for (int i = tid; i < HID_CH * IN_CH; i += 512) {
        sWl[i] = W_l1[i];
        sWr[i] = W_r1[i];
    }
    for (int i = tid; i < HID_CH; i += 512) sb[i] = b_l1[i];
    for (int i = tid; i < OUT_CH * HID_CH; i += 512) {
        sWl2[i] = W_l2[i];
        sWr2[i] = W_r2[i];
    }
    if (tid < OUT_CH) sb2[tid] = b_l2[tid];
    if (tid < 128) scnt[tid] = 0;

    int r = blockIdx.x;
    int len = cursor[r * CSTRIDE];
    if (len > CAP) len = CAP;
    const int* bin = bucket + (size_t)r * CAP;
    for (int j = tid; j < len; j += 512) raw[j] = bin[j];
    __syncthreads();

    for (int j = tid; j < len; j += 512) atomicAdd(&scnt[raw[j] >> 17], 1);
    __syncthreads();

    // Exclusive scan over 128 slots (RN=98 padded): per-wave shfl scan, 2 waves.
    int lane = tid & 63;
    if (tid < 128) {
        int v = scnt[tid];
        int incl = v;
        #pragma unroll
        for (int d = 1; d < 64; d <<= 1) {
            int t2 = __shfl_up(incl, d);
            if (lane >= d) incl += t2;
        }
        if (lane == 63) wtot[tid >> 6] = incl;
        soff[tid] = incl - v;
    }
    __syncthreads();
    if (tid < 128) {
        int o = soff[tid] + ((tid >= 64) ? wtot[0] : 0);
        soff[tid] = o;
        scur[tid] = o;
    }
    __syncthreads();

    for (int j = tid; j < len; j += 512) {
        int w = raw[j];
        int p = atomicAdd(&scur[w >> 17], 1);
        seg[p] = w & 0x1FFFF;
    }
    __syncthreads();

    // Dump node-sorted CSR in place over the bucket region (coalesced).
    int* cw = csr + (size_t)r * CAP;
    for (int j = tid; j < len; j += 512) cw[j] = seg[j];

    // Walk: 4 lanes per node, independent (pipelineable) LDS + global loads.
    int q = tid >> 2;
    int l = tid & 3;
    int node = r * RN + q;
    if (q < RN && node < N_NODES) {
        int o = soff[q];
        int dn = scnt[q];
        if (l == 0) offdeg[node] = o | (dn << 16);

        float acc[IN_CH];
        #pragma unroll
        for (int c = 0; c < IN_CH; c++) acc[c] = 0.0f;
        for (int j = o + l; j < o + dn; j += 4) {
            int s = seg[j];
            const float4* xs = (const float4*)(x + (size_t)s * IN_CH);
            float4 a = xs[0];
            float4 b = xs[1];
            acc[0] += a.x; acc[1] += a.y; acc[2] += a.z; acc[3] += a.w;
            acc[4] += b.x; acc[5] += b.y; acc[6] += b.z; acc[7] += b.w;
        }
        #pragma unroll
        for (int c = 0; c < IN_CH; c++) {
            acc[c] += __shfl_xor(acc[c], 1);
            acc[c] += __shfl_xor(acc[c], 2);
        }
        float inv = 1.0f / fmaxf((float)dn, 1.0f);
        float ag[IN_CH], xa[IN_CH];
        #pragma unroll
        for (int c = 0; c < IN_CH; c++) ag[c] = acc[c] * inv;
        const float4* xp = (const float4*)(x + (size_t)node * IN_CH);
        float4 x0 = xp[0], x1 = xp[1];
        xa[0] = x0.x; xa[1] = x0.y; xa[2] = x0.z; xa[3] = x0.w;
        xa[4] = x1.x; xa[5] = x1.y; xa[6] = x1.z; xa[7] = x1.w;

        // Distributed MLP: lane l handles hidden units [16l, 16l+16).
        float g0 = 0.f, g1 = 0.f, r0 = 0.f, r1 = 0.f;
        int k0 = l * 16;
        #pragma unroll 4
        for (int kk = k0; kk < k0 + 16; kk++) {
            float hk = sb[kk];
            #pragma unroll
            for (int c = 0; c < IN_CH; c++) {
                hk += sWl[kk * IN_CH + c] * ag[c];
                hk += sWr[kk * IN_CH + c] * xa[c];
            }
            hk = fmaxf(hk, 0.0f);   // ReLU (dropout identity in eval)
            g0 += sWl2[kk] * hk;
            g1 += sWl2[HID_CH + kk] * hk;
            r0 += sWr2[kk] * hk;
            r1 += sWr2[HID_CH + kk] * hk;
        }
        g0 += __shfl_xor(g0, 1); g0 += __shfl_xor(g0, 2);
        g1 += __shfl_xor(g1, 1); g1 += __shfl_xor(g1, 2);
        r0 += __shfl_xor(r0, 1); r0 += __shfl_xor(r0, 2);
        r1 += __shfl_xor(r1, 1); r1 += __shfl_xor(r1, 2);
        if (l == 0) {
            g[(size_t)node * 2 + 0] = g0;
            g[(size_t)node * 2 + 1] = g1;
            float2 rt;
            rt.x = r0 + sb2[0];
            rt.y = r1 + sb2[1];
            *(float2*)(out_rt + (size_t)node * 2) = rt;
        }
    }
}

// Layer 2 (round-0 walk): 4 lanes/node read the node's contiguous CSR span
// from global (L1/L2-hot window per range), gather g[src], shfl-reduce;
// out = sum/max(dn,1) + rt. No LDS, no barriers, no atomics.
__global__ __launch_bounds__(256) void sage2_kernel(
        const int* __restrict__ csr, const int* __restrict__ offdeg,
        const float* __restrict__ g, float* __restrict__ out) {
    int t = blockIdx.x * blockDim.x + threadIdx.x;
    int node = t >> 2;
    int l = t & 3;
    if (node >= N_NODES) return;
    int r = node / RN;
    int od = offdeg[node];
    int o = od & 0xFFFF;
    int dn = od >> 16;
    const int* seg = csr + (size_t)r * CAP;
    float a0 = 0.f, a1 = 0.f;
    for (int j = o + l; j < o + dn; j += 4) {
        int s = seg[j];
        float2 gv = *(const float2*)(g + (size_t)s * 2);
        a0 += gv.x;
        a1 += gv.y;
    }
    a0 += __shfl_xor(a0, 1); a0 += __shfl_xor(a0, 2);
    a1 += __shfl_xor(a1, 1); a1 += __shfl_xor(a1, 2);
    if (l == 0) {
        float inv = 1.0f / fmaxf((float)dn, 1.0f);
        float2 rt = *(const float2*)(out + (size_t)node * 2);
        float2 ov;
        ov.x = a0 * inv + rt.x;
        ov.y = a1 * inv + rt.y;
        *(float2*)(out + (size_t)node * 2) = ov;
    }
}

extern "C" void kernel_launch(void* const* d_in, const int* in_sizes, int n_in,
                              void* d_out, int out_size, void* d_ws, size_t ws_size,
                              hipStream_t stream) {
    const float* x    = (const float*)d_in[0];
    const int*   ei   = (const int*)d_in[1];   // [2, N_EDGES] int32 per harness
    const float* W_l1 = (const float*)d_in[2];
    const float* b_l1 = (const float*)d_in[3];
    const float* W_r1 = (const float*)d_in[4];
    const float* W_l2 = (const float*)d_in[5];
    const float* b_l2 = (const float*)d_in[6];
    const float* W_r2 = (const float*)d_in[7];
    float* out = (float*)d_out;

    const int* src = ei;
    const int* dst = ei + N_EDGES;

    int*   cursor = (int*)d_ws;
    int*   bucket = (int*)d_ws + WS_BUCKET;
    int*   offdeg = (int*)d_ws + WS_OFFDEG;
    float* g      = (float*)d_ws + WS_G;

    hipMemsetAsync(cursor, 0, R2 * CSTRIDE * sizeof(int), stream);

    bucket_sort<<<NB, 1024, 0, stream>>>(src, dst, cursor, bucket);
    sage1_range<<<R2, 512, 0, stream>>>(bucket, cursor, x,
                                        W_l1, b_l1, W_r1, W_l2, b_l2, W_r2,
                                        bucket /*csr in place*/, offdeg, g, out);
    sage2_kernel<<<(4 * N_NODES + 255) / 256, 256, 0, stream>>>(bucket, offdeg, g, out);
}

// Round 13
// 133.360 us; speedup vs baseline: 1.0891x; 1.0891x over previous
//
#include <hip/hip_runtime.h>

#define N_NODES 100000
#define N_EDGES 1600000
#define IN_CH 8
#define HID_CH 64
#define OUT_CH 2

// 1024 dst-ranges of 98 nodes (1024*98 = 100352 >= 100000).
#define R2   1024
#define RN   98
#define CAP  1920    // per-range capacity; Binom mean 1568, sd ~40 -> +8.9σ
#define CSTRIDE 16   // cursor padded to one range per 64B line

// Ownership-filtered binning (round-8 structure, best measured: 134.3us
// total). 256 blocks = 32 chunks x 8 owners; chunk = blockIdx&31,
// own = blockIdx>>5 (owners of chunk c all == c mod 8 -> same XCD).
// ROUND-13 CHANGE (the one shared structure all seven 17±3us binning
// variants kept): the scan's RETURNING same-address LDS atomic
// (p=atomicAdd(&wcnt)) + dependent store is replaced by register ballot
// compaction — __ballot(owned) + popcll(mask & lanemask_lt) gives the slot,
// wave-uniform base stays in a register. Zero LDS ops in the scan's hot path
// besides the histogram add; identical traffic and semantics.
#define NCHUNK 32
#define CH_E (N_EDGES / NCHUNK)   // 50000 edges per chunk (25000 int2)
#define NW   16                   // waves per 1024-thread block
#define WSTG 552                  // per-wave staging cap: mean 390, sd 18.5, +8.7σ

// ---- workspace (4-byte words), ~9.1 MB ----
#define WS_BUCKET (R2 * CSTRIDE)
#define WS_OFFDEG (WS_BUCKET + R2 * CAP)
#define WS_G      (WS_OFFDEG + R2 * RN)

__global__ __launch_bounds__(1024) void bucket_own(
        const int* __restrict__ src, const int* __restrict__ dst,
        int* __restrict__ cursor, int* __restrict__ bucket) {
    __shared__ int stg[NW * WSTG];   // staged owned edges, per-wave regions
    __shared__ int wcnt[NW];
    __shared__ int cnt[R2];          // per-block count, owned ranges only
    __shared__ int cur[R2];
    int tid = threadIdx.x;
    int w = tid >> 6;
    int lane = tid & 63;
    unsigned own = blockIdx.x >> 5;  // XCD-colocated ownership
    int chunk = blockIdx.x & 31;
    if (tid < R2) cnt[tid] = 0;
    __syncthreads();

    const int2* d2 = (const int2*)(dst + (size_t)chunk * CH_E);
    const int2* s2 = (const int2*)(src + (size_t)chunk * CH_E);
    int* mystg = stg + w * WSTG;
    unsigned long long ltm = (1ULL << lane) - 1;   // lanemask_lt
    int wbase = 0;                                  // wave-uniform staging base
    for (int i = tid; i < CH_E / 2; i += 1024) {
        int2 d = d2[i];
        int2 s = s2[i];
        unsigned r1 = (unsigned)d.x / RN;
        unsigned r2 = (unsigned)d.y / RN;
        bool o1 = (r1 & 7) == own;
        bool o2 = (r2 & 7) == own;
        // Ballot compaction, edge slot 1. (__ballot sees only active lanes;
        // tail-divergent lanes exited monotonically, lane 0 runs max trips.)
        unsigned long long m1 = __ballot(o1);
        if (o1) {
            int idx = wbase + __popcll(m1 & ltm);
            if (idx < WSTG) {
                unsigned dl = (unsigned)d.x - r1 * RN;
                mystg[idx] = (int)(((r1 >> 3) << 24) | (dl << 17) | (unsigned)s.x);
                atomicAdd(&cnt[r1], 1);
            }
        }
        wbase += (int)__popcll(m1);
        // Edge slot 2.
        unsigned long long m2 = __ballot(o2);
        if (o2) {
            int idx = wbase + __popcll(m2 & ltm);
            if (idx < WSTG) {
                unsigned dl = (unsigned)d.y - r2 * RN;
                mystg[idx] = (int)(((r2 >> 3) << 24) | (dl << 17) | (unsigned)s.y);
                atomicAdd(&cnt[r2], 1);
            }
        }
        wbase += (int)__popcll(m2);
    }
    if (lane == 0) wcnt[w] = (wbase < WSTG) ? wbase : WSTG;
    __syncthreads();

    // Reserve: 128 owned ranges per block -> 32K global atomics total.
    for (int i = tid; i < R2; i += 1024) {
        if (((unsigned)i & 7) == own) {
            int c = cnt[i];
            cur[i] = (c > 0) ? atomicAdd(&cursor[i * CSTRIDE], c) : 0;
        }
    }
    __syncthreads();

    // Place from LDS staging: ~390 edges per wave; spans of ~49 contiguous
    // slots per (block,range) -> mostly full-line, single-writer stores.
    int mycnt = wcnt[w];
    for (int j = lane; j < mycnt; j += 64) {
        int e = mystg[j];
        unsigned r = (((unsigned)e >> 24) << 3) | own;
        int slot = atomicAdd(&cur[r], 1);
        if (slot < CAP)
            bucket[(size_t)r * CAP + slot] = e & 0x00FFFFFF;
    }
}

// Layer 1 (proven sorted structure): LDS counting-sort of the range's edges
// to node order, 4-lane-per-node walk + distributed MLP. Dumps sorted CSR in
// place over the bucket region + offdeg, for the layer-2 gather walk.
__global__ __launch_bounds__(512) void sage1_range(
        const int* __restrict__ bucket, const int* __restrict__ cursor,
        const float* __restrict__ x,
        const float* __restrict__ W_l1, const float* __restrict__ b_l1,
        const float* __restrict__ W_r1,
        const float* __restrict__ W_l2, const float* __restrict__ b_l2,
        const float* __restrict__ W_r2,
        int* __restrict__ csr, int* __restrict__ offdeg,
        float* __restrict__ g, float* __restrict__ out_rt) {
    __shared__ int raw[CAP];
    __shared__ int seg[CAP];
    __shared__ int scnt[128];
    __shared__ int soff[128];
    __shared__ int scur[128];
    __shared__ int wtot[2];
    __shared__ float sWl[HID_CH * IN_CH];
    __shared__ float sWr[HID_CH * IN_CH];
    __shared__ float sb[HID_CH];
    __shared__ float sWl2[OUT_CH * HID_CH];
    __shared__ float sWr2[OUT_CH * HID_CH];
    __shared__ float sb2[OUT_CH];

    int tid = threadIdx.x;
    for (int i = tid; i < HID_CH * IN_CH; i += 512) {
        sWl[i] = W_l1[i];
        sWr[i] = W_r1[i];
    }
    for (int i = tid; i < HID_CH; i += 512) sb[i] = b_l1[i];
    for (int i = tid; i < OUT_CH * HID_CH; i += 512) {
        sWl2[i] = W_l2[i];
        sWr2[i] = W_r2[i];
    }
    if (tid < OUT_CH) sb2[tid] = b_l2[tid];
    if (tid < 128) scnt[tid] = 0;

    int r = blockIdx.x;
    int len = cursor[r * CSTRIDE];
    if (len > CAP) len = CAP;
    const int* bin = bucket + (size_t)r * CAP;
    for (int j = tid; j < len; j += 512) raw[j] = bin[j];
    __syncthreads();

    for (int j = tid; j < len; j += 512) atomicAdd(&scnt[raw[j] >> 17], 1);
    __syncthreads();

    // Exclusive scan over 128 slots (RN=98 padded): per-wave shfl scan, 2 waves.
    int lane = tid & 63;
    if (tid < 128) {
        int v = scnt[tid];
        int incl = v;
        #pragma unroll
        for (int d = 1; d < 64; d <<= 1) {
            int t2 = __shfl_up(incl, d);
            if (lane >= d) incl += t2;
        }
        if (lane == 63) wtot[tid >> 6] = incl;
        soff[tid] = incl - v;
    }
    __syncthreads();
    if (tid < 128) {
        int o = soff[tid] + ((tid >= 64) ? wtot[0] : 0);
        soff[tid] = o;
        scur[tid] = o;
    }
    __syncthreads();

    for (int j = tid; j < len; j += 512) {
        int w = raw[j];
        int p = atomicAdd(&scur[w >> 17], 1);
        seg[p] = w & 0x1FFFF;
    }
    __syncthreads();

    // Dump node-sorted CSR in place over the bucket region (coalesced).
    int* cw = csr + (size_t)r * CAP;
    for (int j = tid; j < len; j += 512) cw[j] = seg[j];

    // Walk: 4 lanes per node, independent (pipelineable) LDS + global loads.
    int q = tid >> 2;
    int l = tid & 3;
    int node = r * RN + q;
    if (q < RN && node < N_NODES) {
        int o = soff[q];
        int dn = scnt[q];
        if (l == 0) offdeg[node] = o | (dn << 16);

        float acc[IN_CH];
        #pragma unroll
        for (int c = 0; c < IN_CH; c++) acc[c] = 0.0f;
        for (int j = o + l; j < o + dn; j += 4) {
            int s = seg[j];
            const float4* xs = (const float4*)(x + (size_t)s * IN_CH);
            float4 a = xs[0];
            float4 b = xs[1];
            acc[0] += a.x; acc[1] += a.y; acc[2] += a.z; acc[3] += a.w;
            acc[4] += b.x; acc[5] += b.y; acc[6] += b.z; acc[7] += b.w;
        }
        #pragma unroll
        for (int c = 0; c < IN_CH; c++) {
            acc[c] += __shfl_xor(acc[c], 1);
            acc[c] += __shfl_xor(acc[c], 2);
        }
        float inv = 1.0f / fmaxf((float)dn, 1.0f);
        float ag[IN_CH], xa[IN_CH];
        #pragma unroll
        for (int c = 0; c < IN_CH; c++) ag[c] = acc[c] * inv;
        const float4* xp = (const float4*)(x + (size_t)node * IN_CH);
        float4 x0 = xp[0], x1 = xp[1];
        xa[0] = x0.x; xa[1] = x0.y; xa[2] = x0.z; xa[3] = x0.w;
        xa[4] = x1.x; xa[5] = x1.y; xa[6] = x1.z; xa[7] = x1.w;

        // Distributed MLP: lane l handles hidden units [16l, 16l+16).
        float g0 = 0.f, g1 = 0.f, r0 = 0.f, r1 = 0.f;
        int k0 = l * 16;
        #pragma unroll 4
        for (int kk = k0; kk < k0 + 16; kk++) {
            float hk = sb[kk];
            #pragma unroll
            for (int c = 0; c < IN_CH; c++) {
                hk += sWl[kk * IN_CH + c] * ag[c];
                hk += sWr[kk * IN_CH + c] * xa[c];
            }
            hk = fmaxf(hk, 0.0f);   // ReLU (dropout identity in eval)
            g0 += sWl2[kk] * hk;
            g1 += sWl2[HID_CH + kk] * hk;
            r0 += sWr2[kk] * hk;
            r1 += sWr2[HID_CH + kk] * hk;
        }
        g0 += __shfl_xor(g0, 1); g0 += __shfl_xor(g0, 2);
        g1 += __shfl_xor(g1, 1); g1 += __shfl_xor(g1, 2);
        r0 += __shfl_xor(r0, 1); r0 += __shfl_xor(r0, 2);
        r1 += __shfl_xor(r1, 1); r1 += __shfl_xor(r1, 2);
        if (l == 0) {
            g[(size_t)node * 2 + 0] = g0;
            g[(size_t)node * 2 + 1] = g1;
            float2 rt;
            rt.x = r0 + sb2[0];
            rt.y = r1 + sb2[1];
            *(float2*)(out_rt + (size_t)node * 2) = rt;
        }
    }
}

// Layer 2 (round-0 walk): 4 lanes/node read the node's contiguous CSR span
// from global (L1/L2-hot window per range), gather g[src], shfl-reduce;
// out = sum/max(dn,1) + rt. No LDS, no barriers, no atomics.
__global__ __launch_bounds__(256) void sage2_kernel(
        const int* __restrict__ csr, const int* __restrict__ offdeg,
        const float* __restrict__ g, float* __restrict__ out) {
    int t = blockIdx.x * blockDim.x + threadIdx.x;
    int node = t >> 2;
    int l = t & 3;
    if (node >= N_NODES) return;
    int r = node / RN;
    int od = offdeg[node];
    int o = od & 0xFFFF;
    int dn = od >> 16;
    const int* seg = csr + (size_t)r * CAP;
    float a0 = 0.f, a1 = 0.f;
    for (int j = o + l; j < o + dn; j += 4) {
        int s = seg[j];
        float2 gv = *(const float2*)(g + (size_t)s * 2);
        a0 += gv.x;
        a1 += gv.y;
    }
    a0 += __shfl_xor(a0, 1); a0 += __shfl_xor(a0, 2);
    a1 += __shfl_xor(a1, 1); a1 += __shfl_xor(a1, 2);
    if (l == 0) {
        float inv = 1.0f / fmaxf((float)dn, 1.0f);
        float2 rt = *(const float2*)(out + (size_t)node * 2);
        float2 ov;
        ov.x = a0 * inv + rt.x;
        ov.y = a1 * inv + rt.y;
        *(float2*)(out + (size_t)node * 2) = ov;
    }
}

extern "C" void kernel_launch(void* const* d_in, const int* in_sizes, int n_in,
                              void* d_out, int out_size, void* d_ws, size_t ws_size,
                              hipStream_t stream) {
    const float* x    = (const float*)d_in[0];
    const int*   ei   = (const int*)d_in[1];   // [2, N_EDGES] int32 per harness
    const float* W_l1 = (const float*)d_in[2];
    const float* b_l1 = (const float*)d_in[3];
    const float* W_r1 = (const float*)d_in[4];
    const float* W_l2 = (const float*)d_in[5];
    const float* b_l2 = (const float*)d_in[6];
    const float* W_r2 = (const float*)d_in[7];
    float* out = (float*)d_out;

    const int* src = ei;
    const int* dst = ei + N_EDGES;

    int*   cursor = (int*)d_ws;
    int*   bucket = (int*)d_ws + WS_BUCKET;
    int*   offdeg = (int*)d_ws + WS_OFFDEG;
    float* g      = (float*)d_ws + WS_G;

    hipMemsetAsync(cursor, 0, R2 * CSTRIDE * sizeof(int), stream);

    bucket_own<<<NCHUNK * 8, 1024, 0, stream>>>(src, dst, cursor, bucket);
    sage1_range<<<R2, 512, 0, stream>>>(bucket, cursor, x,
                                        W_l1, b_l1, W_r1, W_l2, b_l2, W_r2,
                                        bucket /*csr in place*/, offdeg, g, out);
    sage2_kernel<<<(4 * N_NODES + 255) / 256, 256, 0, stream>>>(bucket, offdeg, g, out);
}